// Round 6
// baseline (249.006 us; speedup 1.0000x reference)
//
#include <hip/hip_runtime.h>
#include <hip/hip_fp16.h>
#include <stdint.h>

// Problem dims (fixed by reference)
// Reference dtypes: x fp16, bias fp16, out fp16 -> harness passes/reads FLOAT32.
// packed_w int32 (8192 x 512), 16 two-bit codes per word, values {0,1,3}.
#define M_DIM 1024
#define N_DIM 8192
#define K_DIM 8192
#define KP    (K_DIM / 16)   // 512 packed int32 words per weight row

#define BM 64                 // 1024 blocks -> 4 blocks/CU
#define BN 128
#define BK 64
#define NTHREADS 256
#define B_STRIDE 144          // fallback kernel only

// Transposed A workspace layout (bytes), built by cvt_x_t (UNCHANGED, 128-row slabs):
//   slab(8):2 MiB | kt(128):16 KiB | i32(4):4 KiB | ks(4):1 KiB | q(2):512 | r(32):16
// A-fragment (i32, ks) = contiguous 1 KB at base + lane*16 (lane = q*32+r).
// A 64-row block tile = i32 groups {i32b, i32b+1} of slab mt>>1, i32b=(mt&1)*2.
#define MT_STRIDE 2097152
#define KT_STRIDE 16384

typedef _Float16 half8   __attribute__((ext_vector_type(8)));
typedef __fp16   fp16x2  __attribute__((ext_vector_type(2)));
typedef float    f32x4   __attribute__((ext_vector_type(4)));
typedef float    f32x16  __attribute__((ext_vector_type(16)));

__device__ __forceinline__ uint32_t cvt2(float a, float b) {
  fp16x2 p = __builtin_amdgcn_cvt_pkrtz(a, b);   // RTZ exact: values are fp16-representable
  return __builtin_bit_cast(uint32_t, p);
}

// Async global->LDS 16B copy. LDS dest is wave-uniform base + lane*16 (HW rule),
// so the LDS base passed here must be wave-uniform and the global ptr per-lane.
__device__ __forceinline__ void gload_lds16(const char* g, char* l) {
  __builtin_amdgcn_global_load_lds(
      (const __attribute__((address_space(1))) void*)g,
      (__attribute__((address_space(3))) void*)l, 16, 0, 0);
}

// ---- consumer-side half-word ternary decode (verified R8) ----
// word = 16 codes; quad half (sh = quad*16) = 8 codes -> half8 MFMA B-fragment.
// T byte-table [0x00,0x3C,0x06,0x42] = fp16 hi-bytes of {0,1,2,3} (low byte always 0).
__device__ __forceinline__ half8 dec_frag(uint32_t word, uint32_t sh) {
  const uint32_t T = 0x42063C00u;
  uint32_t h  = (word >> sh) & 0xFFFFu;
  uint32_t W  = (h & 0x3333u) | ((h << 14) & 0x33330000u);
  uint32_t c0 = __builtin_amdgcn_perm(0u, W, 0x04040200u);  // W.b0 | W.b2<<8
  uint32_t c1 = __builtin_amdgcn_perm(0u, W, 0x04040301u);  // W.b1 | W.b3<<8
  uint32_t s0 = (c0 * 0x1001u) & 0x03030303u;               // [c0,c1,c2,c3]
  uint32_t s1 = (c1 * 0x1001u) & 0x03030303u;               // [c4,c5,c6,c7]
  uint32_t P0 = __builtin_amdgcn_perm(0u, T, s0);
  uint32_t P1 = __builtin_amdgcn_perm(0u, T, s1);
  uint4 v;
  v.x = __builtin_amdgcn_perm(P0, 0u, 0x05000400u);  // fp16(c0), fp16(c1)
  v.y = __builtin_amdgcn_perm(P0, 0u, 0x07000600u);  // fp16(c2), fp16(c3)
  v.z = __builtin_amdgcn_perm(P1, 0u, 0x05000400u);  // fp16(c4), fp16(c5)
  v.w = __builtin_amdgcn_perm(P1, 0u, 0x07000600u);  // fp16(c6), fp16(c7)
  return __builtin_bit_cast(half8, v);
}

// ---- pre-pass: x f32 -> fp16, transposed-tiled into workspace (R8, verified) ----
__global__ __launch_bounds__(256)
void cvt_x_t(const float* __restrict__ x, char* __restrict__ xhT) {
  __shared__ __align__(16) char st[16384];
  const int b  = blockIdx.x;
  const int mt = b >> 7, kt = b & 127;
  const int t  = threadIdx.x;
#pragma unroll
  for (int p = 0; p < 8; ++p) {
    int f   = t + 256 * p;
    int R   = f >> 4;
    int cc4 = f & 15;
    float4 v = *(const float4*)(x + (size_t)(mt * 128 + R) * K_DIM + kt * 64 + cc4 * 4);
    uint32_t w0 = cvt2(v.x, v.y), w1 = cvt2(v.z, v.w);
    int c8 = cc4 >> 1, hh = cc4 & 1;
    int i32 = R >> 5, r = R & 31, ks = c8 >> 1, q = c8 & 1;
    *(uint2*)(st + i32 * 4096 + ks * 1024 + q * 512 + r * 16 + hh * 8) = make_uint2(w0, w1);
  }
  __syncthreads();
  char* outb = xhT + (size_t)mt * MT_STRIDE + (size_t)kt * KT_STRIDE;
#pragma unroll
  for (int e = 0; e < 4; ++e) {
    int d = (e * 256 + t) * 16;
    *(uint4*)(outb + d) = *(const uint4*)(st + d);
  }
}

// ====== fast path ======
// R14: R13 UNCHANGED except a one-time block-phase stagger at kernel entry.
// Convoy theory: R8/R11/R13 (three different dataflows, 2x occupancy delta)
// all land at ~155 us because co-resident blocks run time-aligned identical
// barrier cadences: every block's LDS-read burst / decode burst / MFMA burst
// hits the shared CU resources at the same moment -> bursts serialize
// (wall ~= SUM of per-block step demands; no single resource >60% busy).
// Fix: offset block start times by quarter-step (step ~2976 cyc) so bursts
// from different blocks interleave. s_sleep = pure delay, zero correctness risk.
__global__ __launch_bounds__(NTHREADS, 4)
void ternary_gemm_dc(const char* __restrict__ xhT,
                     const int*  __restrict__ pw,
                     const float* __restrict__ bias,
                     float*       __restrict__ out) {
  __shared__ __align__(16) char Ast[3 * 8192];   // A fp16 64x64 tiles, 3-deep (ws layout)
  __shared__ __align__(16) char stg[3 * 2048];   // raw packed B words: 128 rows x int4, 3-deep

  const int tid  = threadIdx.x;
  const int lane = tid & 63;
  const int w    = tid >> 6;          // 0..3 = N-quarter of the block tile
  const int bid  = blockIdx.x;
  // XCD swizzle (bijective): xcd = bid&7 gets mt in {2*xcd, 2*xcd+1} -> each
  // XCD keeps 2 A-slabs (2 MiB) hot in its L2 across its resident blocks.
  const int xcd = bid & 7;
  const int mt  = xcd * 2 + ((bid >> 3) & 1);   // 0..15
  const int nt  = bid >> 4;                      // 0..63
  const int bm  = mt * BM;
  const int bn  = nt * BN;
  const int slab = mt >> 1;
  const int i32b = (mt & 1) * 2;                 // first i32 group of this 64-row tile

  // ---- R14 stagger: blocks likely co-resident on a CU differ in (bid>>3).
  // Offsets 0 / ~770 / ~1540 / ~2300 cycles (s_sleep N = ~64*N cyc).
  {
    const int ph = (bid >> 3) & 3;
    if (ph & 1) asm volatile("s_sleep 12");
    if (ph & 2) asm volatile("s_sleep 24");
  }

  // A staging: block's 8 KB chunk = [i32b*4096, i32b*4096+8192) of each kt-block.
  // Wave w copies 2 KB: 2 insts of 16B/lane, linear.
  const char* gAs = xhT + (size_t)slab * MT_STRIDE + i32b * 4096 + w * 2048 + lane * 16;

  // B word staging: thread t -> row t>>1, word-pair t&1 (int2, coalesced global load)
  const int rT = tid >> 1, hT = tid & 1;
  const int2* gB = (const int2*)pw + (size_t)(bn + rT) * (KP / 2) + hT;
  const int stOff = rT * 16 + hT * 8;

  // Consumer row: this wave's 32 N-columns = W-rows w*32 + (lane&31)
  const int rowOff = (w * 32 + (lane & 31)) * 16;
  const uint32_t sh = (lane >> 5) * 16;   // quad selects codes 0-7 vs 8-15 of each word

  // A fragment read base: buf/ig/ks folded into ds_read immediate offsets
  const char* const aPtr = Ast + lane * 16;   // + buf*8192 + ig*4096 + ks*1024

  f32x16 acc[2];
#pragma unroll
  for (int i = 0; i < 2; ++i) acc[i] = (f32x16)(0.f);

  const int NT = K_DIM / BK;   // 128

  auto stageA = [&](int buf, int kt) {
    const char* g = gAs + (size_t)kt * KT_STRIDE;
    char* lbase = Ast + buf * 8192 + w * 2048;   // wave-uniform LDS base
#pragma unroll
    for (int e = 0; e < 2; ++e)
      gload_lds16(g + e * 1024, lbase + e * 1024);
  };

  // ---- prologue: A(0)->buf0, A(1)->buf1 (async); words(0)->stg0; words(1)->regs ----
  stageA(0, 0);
  stageA(1, 1);
  int2 wfirst = gB[0];
  *(int2*)(stg + stOff) = wfirst;
  int2 wcur = gB[2];                 // tile 1 words
  __syncthreads();                   // full drain ONCE: A0,A1 + B0 ready

  int2 wnxt;
  // step: cur/counted literal at every call site -> offsets and barriers fold.
  auto step = [&](int cur, int kt, bool counted) {
    // Issue next-next B words FIRST (oldest VMEM), then A-stage(kt+2):
    // the ds_write of wcur next step then only drains the oldest entry.
    int kn2 = (kt + 2 < NT) ? (kt + 2) : (NT - 1);
    wnxt = gB[kn2 * 2];
    if (kt + 2 < NT) stageA((cur + 2) % 3, kt + 2);

    // Read this tile's raw words (1 row x int4); write next tile's words
    uint32_t wr[4];
    *(uint4*)wr = *(const uint4*)(stg + cur * 2048 + rowOff);
    *(int2*)(stg + ((cur + 1) % 3) * 2048 + stOff) = wcur;

    // Compute: A frags from LDS (immediate offsets), decode B in-register
#pragma unroll
    for (int ks = 0; ks < 4; ++ks) {
      half8 a0 = *(const half8*)(aPtr + cur * 8192 + 0 * 4096 + ks * 1024);
      half8 a1 = *(const half8*)(aPtr + cur * 8192 + 1 * 4096 + ks * 1024);
      half8 bf = dec_frag(wr[ks], sh);
      acc[0] = __builtin_amdgcn_mfma_f32_32x32x16_f16(a0, bf, acc[0], 0, 0, 0);
      acc[1] = __builtin_amdgcn_mfma_f32_32x32x16_f16(a1, bf, acc[1], 0, 0, 0);
    }

    if (counted) {
      // T4: keep this step's 3 VMEM ops (1 gB + 2 gload_lds) in flight across
      // the barrier; everything older (stage kt+1, prev gB) is forced complete.
      __builtin_amdgcn_sched_barrier(0);
      asm volatile("s_waitcnt vmcnt(3) lgkmcnt(0)" ::: "memory");
      __builtin_amdgcn_s_barrier();
      asm volatile("" ::: "memory");
      __builtin_amdgcn_sched_barrier(0);
    } else {
      __syncthreads();
    }
    wcur = wnxt;
  };

  for (int kt = 0; kt < NT - 2; kt += 3) {   // 42 chunks of 3: cur pattern 0,1,2
    step(0, kt, true);
    step(1, kt + 1, true);
    step(2, kt + 2, true);
  }
  step(0, NT - 2, false);   // tail: full drains, no staging (kt+2 >= NT)
  step(1, NT - 1, false);

  // Epilogue: 32x32 C/D (m74/m101): col(n)=lane&31, row(m)=(reg&3)+8*(reg>>2)+4*(lane>>5)
  // fp16 rounding replicated exactly: f16(y) + f16(bias) in half, widen to f32.
  {
    int n = bn + w * 32 + (lane & 31);
    __half hb = __float2half_rn(bias[n]);
#pragma unroll
    for (int ig = 0; ig < 2; ++ig) {
      int mbase = bm + ig * 32 + 4 * (lane >> 5);
#pragma unroll
      for (int reg = 0; reg < 16; ++reg) {
        int m = mbase + (reg & 3) + 8 * (reg >> 2);
        __half hy = __float2half_rn(acc[ig][reg]);
        out[(size_t)m * N_DIM + n] = __half2float(__hadd(hy, hb));
      }
    }
  }
}

// ================= fallback (R4 kernel, known-good): used only if ws too small =================
__device__ __forceinline__ uint32_t unpack_pair16(uint32_t u, int p) {
  uint32_t c0 = (u >> (4 * p)) & 3u;
  uint32_t c1 = (u >> (4 * p + 2)) & 3u;
  uint32_t lo = (c0 & 1u) * 0x3C00u + (c0 >> 1) * 0x0600u;
  uint32_t hi = (c1 & 1u) * 0x3C00u + (c1 >> 1) * 0x0600u;
  return lo | (hi << 16);
}

__global__ __launch_bounds__(NTHREADS, 2)
void ternary_gemm(const float* __restrict__ x,
                  const int*   __restrict__ pw,
                  const float* __restrict__ bias,
                  float*       __restrict__ out) {
  __shared__ __align__(16) char AsB[128 * B_STRIDE];
  __shared__ __align__(16) char BsB[128 * B_STRIDE];

  const int tid  = threadIdx.x;
  const int lane = tid & 63;
  const int w    = tid >> 6;
  const int wm   = w >> 1, wn = w & 1;
  const int bid  = blockIdx.x;
  const int bm   = (bid & 7) * 128;
  const int bn   = (bid >> 3) * 128;

  const int rT = tid >> 1, hT = tid & 1;
  const float* gA = x + (size_t)(bm + rT) * K_DIM + hT * 32;
  char* const  lA = AsB + rT * B_STRIDE + hT * 64;
  const int2* gB = (const int2*)pw + (size_t)(bn + rT) * (KP / 2) + hT;
  char* dBp[4];
#pragma unroll
  for (int h = 0; h < 4; ++h)
    dBp[h] = BsB + rT * B_STRIDE + (hT * 4 + h) * 16;

  int offA[4][2], offB[4][2];
#pragma unroll
  for (int i = 0; i < 4; ++i)
#pragma unroll
    for (int ks = 0; ks < 2; ++ks) {
      int c = ks * 4 + (lane >> 4);
      offA[i][ks] = (wm * 64 + i * 16 + (lane & 15)) * B_STRIDE + c * 16;
      offB[i][ks] = (wn * 64 + i * 16 + (lane & 15)) * B_STRIDE + c * 16;
    }

  f32x4 acc[4][4];
#pragma unroll
  for (int i = 0; i < 4; ++i)
#pragma unroll
    for (int j = 0; j < 4; ++j)
      acc[i][j] = (f32x4){0.f, 0.f, 0.f, 0.f};

  const int NT = K_DIM / BK;
  for (int kt = 0; kt < NT; ++kt) {
    __syncthreads();
    int2 wcur = gB[kt * 2];
    float4 av[8];
#pragma unroll
    for (int v = 0; v < 8; ++v) av[v] = *(const float4*)(gA + kt * BK + v * 4);
    uint32_t d0[8], d1[8];
#pragma unroll
    for (int p = 0; p < 8; ++p) d0[p] = unpack_pair16((uint32_t)wcur.x, p);
#pragma unroll
    for (int p = 0; p < 8; ++p) d1[p] = unpack_pair16((uint32_t)wcur.y, p);
    *(uint4*)dBp[0] = make_uint4(d0[0], d0[1], d0[2], d0[3]);
    *(uint4*)dBp[1] = make_uint4(d0[4], d0[5], d0[6], d0[7]);
    *(uint4*)dBp[2] = make_uint4(d1[0], d1[1], d1[2], d1[3]);
    *(uint4*)dBp[3] = make_uint4(d1[4], d1[5], d1[6], d1[7]);
#pragma unroll
    for (int v = 0; v < 4; ++v) {
      uint4 aw;
      aw.x = cvt2(av[2 * v].x, av[2 * v].y);
      aw.y = cvt2(av[2 * v].z, av[2 * v].w);
      aw.z = cvt2(av[2 * v + 1].x, av[2 * v + 1].y);
      aw.w = cvt2(av[2 * v + 1].z, av[2 * v + 1].w);
      *(uint4*)(lA + v * 16) = aw;
    }
    __syncthreads();
#pragma unroll
    for (int ks = 0; ks < 2; ++ks) {
      half8 af[4], bf[4];
#pragma unroll
      for (int i = 0; i < 4; ++i) af[i] = *(const half8*)(AsB + offA[i][ks]);
#pragma unroll
      for (int j = 0; j < 4; ++j) bf[j] = *(const half8*)(BsB + offB[j][ks]);
#pragma unroll
      for (int i = 0; i < 4; ++i)
#pragma unroll
        for (int j = 0; j < 4; ++j)
          acc[i][j] = __builtin_amdgcn_mfma_f32_16x16x32_f16(af[i], bf[j], acc[i][j], 0, 0, 0);
    }
  }
#pragma unroll
  for (int j = 0; j < 4; ++j) {
    int n = bn + wn * 64 + j * 16 + (lane & 15);
    __half hb = __float2half_rn(bias[n]);
#pragma unroll
    for (int i = 0; i < 4; ++i) {
      int m0 = bm + wm * 64 + i * 16 + (lane >> 4) * 4;
#pragma unroll
      for (int r = 0; r < 4; ++r) {
        __half hy = __float2half_rn(acc[i][j][r]);
        out[(size_t)(m0 + r) * N_DIM + n] = __half2float(__hadd(hy, hb));
      }
    }
  }
}

extern "C" void kernel_launch(void* const* d_in, const int* in_sizes, int n_in,
                              void* d_out, int out_size, void* d_ws, size_t ws_size,
                              hipStream_t stream) {
  (void)in_sizes; (void)n_in; (void)out_size;
  const float* x    = (const float*)d_in[0];
  const int*   pwp  = (const int*)d_in[1];
  const float* bias = (const float*)d_in[2];
  float*       outp = (float*)d_out;

  const size_t need = (size_t)M_DIM * K_DIM * 2;   // 16 MiB fp16 x (transposed)
  if (ws_size >= need) {
    char* xhT = (char*)d_ws;
    cvt_x_t<<<8 * 128, 256, 0, stream>>>(x, xhT);
    dim3 grid((M_DIM / BM) * (N_DIM / BN));        // 1024 blocks = 4 per CU
    ternary_gemm_dc<<<grid, NTHREADS, 0, stream>>>(xhT, pwp, bias, outp);
  } else {
    dim3 grid((M_DIM / 128) * (N_DIM / 128));      // 512 blocks
    ternary_gemm<<<grid, NTHREADS, 0, stream>>>(x, pwp, bias, outp);
  }
}

// Round 7
// 243.781 us; speedup vs baseline: 1.0214x; 1.0214x over previous
//
#include <hip/hip_runtime.h>
#include <hip/hip_fp16.h>
#include <stdint.h>

// Problem dims (fixed by reference)
// Reference dtypes: x fp16, bias fp16, out fp16 -> harness passes/reads FLOAT32.
// packed_w int32 (8192 x 512), 16 two-bit codes per word, values {0,1,3}.
#define M_DIM 1024
#define N_DIM 8192
#define K_DIM 8192
#define KP    (K_DIM / 16)   // 512 packed int32 words per weight row

#define BM 64                 // 1024 blocks -> 4 blocks/CU
#define BN 128
#define BK 64
#define NTHREADS 256
#define B_STRIDE 144          // fallback kernel only

// Transposed A workspace layout (bytes), built by cvt_x_t (UNCHANGED, 128-row slabs):
//   slab(8):2 MiB | kt(128):16 KiB | i32(4):4 KiB | ks(4):1 KiB | q(2):512 | r(32):16
// A-fragment (i32, ks) = contiguous 1 KB at base + lane*16 (lane = q*32+r).
// A 64-row block tile = i32 groups {i32b, i32b+1} of slab mt>>1, i32b=(mt&1)*2.
#define MT_STRIDE 2097152
#define KT_STRIDE 16384

typedef _Float16 half8   __attribute__((ext_vector_type(8)));
typedef __fp16   fp16x2  __attribute__((ext_vector_type(2)));
typedef float    f32x4   __attribute__((ext_vector_type(4)));
typedef float    f32x16  __attribute__((ext_vector_type(16)));

__device__ __forceinline__ uint32_t cvt2(float a, float b) {
  fp16x2 p = __builtin_amdgcn_cvt_pkrtz(a, b);   // RTZ exact: values are fp16-representable
  return __builtin_bit_cast(uint32_t, p);
}

// Async global->LDS 16B copy. LDS dest is wave-uniform base + lane*16 (HW rule),
// so the LDS base passed here must be wave-uniform and the global ptr per-lane.
__device__ __forceinline__ void gload_lds16(const char* g, char* l) {
  __builtin_amdgcn_global_load_lds(
      (const __attribute__((address_space(1))) void*)g,
      (__attribute__((address_space(3))) void*)l, 16, 0, 0);
}

// ---- consumer-side half-word ternary decode (verified R8) ----
// word = 16 codes; quad half (sh = quad*16) = 8 codes -> half8 MFMA B-fragment.
// T byte-table [0x00,0x3C,0x06,0x42] = fp16 hi-bytes of {0,1,2,3} (low byte always 0).
__device__ __forceinline__ half8 dec_frag(uint32_t word, uint32_t sh) {
  const uint32_t T = 0x42063C00u;
  uint32_t h  = (word >> sh) & 0xFFFFu;
  uint32_t W  = (h & 0x3333u) | ((h << 14) & 0x33330000u);
  uint32_t c0 = __builtin_amdgcn_perm(0u, W, 0x04040200u);  // W.b0 | W.b2<<8
  uint32_t c1 = __builtin_amdgcn_perm(0u, W, 0x04040301u);  // W.b1 | W.b3<<8
  uint32_t s0 = (c0 * 0x1001u) & 0x03030303u;               // [c0,c1,c2,c3]
  uint32_t s1 = (c1 * 0x1001u) & 0x03030303u;               // [c4,c5,c6,c7]
  uint32_t P0 = __builtin_amdgcn_perm(0u, T, s0);
  uint32_t P1 = __builtin_amdgcn_perm(0u, T, s1);
  uint4 v;
  v.x = __builtin_amdgcn_perm(P0, 0u, 0x05000400u);  // fp16(c0), fp16(c1)
  v.y = __builtin_amdgcn_perm(P0, 0u, 0x07000600u);  // fp16(c2), fp16(c3)
  v.z = __builtin_amdgcn_perm(P1, 0u, 0x05000400u);  // fp16(c4), fp16(c5)
  v.w = __builtin_amdgcn_perm(P1, 0u, 0x07000600u);  // fp16(c6), fp16(c7)
  return __builtin_bit_cast(half8, v);
}

// ---- pre-pass: x f32 -> fp16, transposed-tiled into workspace (R8, verified) ----
__global__ __launch_bounds__(256)
void cvt_x_t(const float* __restrict__ x, char* __restrict__ xhT) {
  __shared__ __align__(16) char st[16384];
  const int b  = blockIdx.x;
  const int mt = b >> 7, kt = b & 127;
  const int t  = threadIdx.x;
#pragma unroll
  for (int p = 0; p < 8; ++p) {
    int f   = t + 256 * p;
    int R   = f >> 4;
    int cc4 = f & 15;
    float4 v = *(const float4*)(x + (size_t)(mt * 128 + R) * K_DIM + kt * 64 + cc4 * 4);
    uint32_t w0 = cvt2(v.x, v.y), w1 = cvt2(v.z, v.w);
    int c8 = cc4 >> 1, hh = cc4 & 1;
    int i32 = R >> 5, r = R & 31, ks = c8 >> 1, q = c8 & 1;
    *(uint2*)(st + i32 * 4096 + ks * 1024 + q * 512 + r * 16 + hh * 8) = make_uint2(w0, w1);
  }
  __syncthreads();
  char* outb = xhT + (size_t)mt * MT_STRIDE + (size_t)kt * KT_STRIDE;
#pragma unroll
  for (int e = 0; e < 4; ++e) {
    int d = (e * 256 + t) * 16;
    *(uint4*)(outb + d) = *(const uint4*)(st + d);
  }
}

// ====== fast path ======
// R15: R13 UNCHANGED except the block-phase stagger now uses the CORRECT key.
// R14 bug: with 1024 blocks on 256 CUs, co-resident blocks are bid+{0,256,512,
// 768} (XCD=bid%8, CU=(bid/8)%32). (bid>>3)&3 is INVARIANT under bid+=256
// ((bid>>3+32k)&3 unchanged) -> all co-resident blocks slept identically; the
// convoy theory was never tested. Correct key: (bid>>8)&3 distinguishes the 4
// co-resident groups -> offsets 0/~770/~1540/~2300 cyc (quarter of the ~2980
// cyc step). Convoy theory: identical barrier cadences of co-resident blocks
// serialize their LDS/decode/MFMA bursts (wall ~= sum of per-block demands;
// no single pipe >60%). Anti-phase lets bursts interleave.
__global__ __launch_bounds__(NTHREADS, 4)
void ternary_gemm_dc(const char* __restrict__ xhT,
                     const int*  __restrict__ pw,
                     const float* __restrict__ bias,
                     float*       __restrict__ out) {
  __shared__ __align__(16) char Ast[3 * 8192];   // A fp16 64x64 tiles, 3-deep (ws layout)
  __shared__ __align__(16) char stg[3 * 2048];   // raw packed B words: 128 rows x int4, 3-deep

  const int tid  = threadIdx.x;
  const int lane = tid & 63;
  const int w    = tid >> 6;          // 0..3 = N-quarter of the block tile
  const int bid  = blockIdx.x;
  // XCD swizzle (bijective): xcd = bid&7 gets mt in {2*xcd, 2*xcd+1} -> each
  // XCD keeps 2 A-slabs (2 MiB) hot in its L2 across its resident blocks.
  const int xcd = bid & 7;
  const int mt  = xcd * 2 + ((bid >> 3) & 1);   // 0..15
  const int nt  = bid >> 4;                      // 0..63
  const int bm  = mt * BM;
  const int bn  = nt * BN;
  const int slab = mt >> 1;
  const int i32b = (mt & 1) * 2;                 // first i32 group of this 64-row tile

  // ---- R15 stagger (FIXED KEY): co-resident blocks differ in bid>>8.
  // Offsets 0 / ~770 / ~1540 / ~2300 cycles (s_sleep N ~= 64*N cyc).
  {
    const int ph = (bid >> 8) & 3;
    if (ph & 1) asm volatile("s_sleep 12");
    if (ph & 2) asm volatile("s_sleep 24");
  }

  // A staging: block's 8 KB chunk = [i32b*4096, i32b*4096+8192) of each kt-block.
  // Wave w copies 2 KB: 2 insts of 16B/lane, linear.
  const char* gAs = xhT + (size_t)slab * MT_STRIDE + i32b * 4096 + w * 2048 + lane * 16;

  // B word staging: thread t -> row t>>1, word-pair t&1 (int2, coalesced global load)
  const int rT = tid >> 1, hT = tid & 1;
  const int2* gB = (const int2*)pw + (size_t)(bn + rT) * (KP / 2) + hT;
  const int stOff = rT * 16 + hT * 8;

  // Consumer row: this wave's 32 N-columns = W-rows w*32 + (lane&31)
  const int rowOff = (w * 32 + (lane & 31)) * 16;
  const uint32_t sh = (lane >> 5) * 16;   // quad selects codes 0-7 vs 8-15 of each word

  // A fragment read base: buf/ig/ks folded into ds_read immediate offsets
  const char* const aPtr = Ast + lane * 16;   // + buf*8192 + ig*4096 + ks*1024

  f32x16 acc[2];
#pragma unroll
  for (int i = 0; i < 2; ++i) acc[i] = (f32x16)(0.f);

  const int NT = K_DIM / BK;   // 128

  auto stageA = [&](int buf, int kt) {
    const char* g = gAs + (size_t)kt * KT_STRIDE;
    char* lbase = Ast + buf * 8192 + w * 2048;   // wave-uniform LDS base
#pragma unroll
    for (int e = 0; e < 2; ++e)
      gload_lds16(g + e * 1024, lbase + e * 1024);
  };

  // ---- prologue: A(0)->buf0, A(1)->buf1 (async); words(0)->stg0; words(1)->regs ----
  stageA(0, 0);
  stageA(1, 1);
  int2 wfirst = gB[0];
  *(int2*)(stg + stOff) = wfirst;
  int2 wcur = gB[2];                 // tile 1 words
  __syncthreads();                   // full drain ONCE: A0,A1 + B0 ready

  int2 wnxt;
  // step: cur/counted literal at every call site -> offsets and barriers fold.
  auto step = [&](int cur, int kt, bool counted) {
    // Issue next-next B words FIRST (oldest VMEM), then A-stage(kt+2):
    // the ds_write of wcur next step then only drains the oldest entry.
    int kn2 = (kt + 2 < NT) ? (kt + 2) : (NT - 1);
    wnxt = gB[kn2 * 2];
    if (kt + 2 < NT) stageA((cur + 2) % 3, kt + 2);

    // Read this tile's raw words (1 row x int4); write next tile's words
    uint32_t wr[4];
    *(uint4*)wr = *(const uint4*)(stg + cur * 2048 + rowOff);
    *(int2*)(stg + ((cur + 1) % 3) * 2048 + stOff) = wcur;

    // Compute: A frags from LDS (immediate offsets), decode B in-register
#pragma unroll
    for (int ks = 0; ks < 4; ++ks) {
      half8 a0 = *(const half8*)(aPtr + cur * 8192 + 0 * 4096 + ks * 1024);
      half8 a1 = *(const half8*)(aPtr + cur * 8192 + 1 * 4096 + ks * 1024);
      half8 bf = dec_frag(wr[ks], sh);
      acc[0] = __builtin_amdgcn_mfma_f32_32x32x16_f16(a0, bf, acc[0], 0, 0, 0);
      acc[1] = __builtin_amdgcn_mfma_f32_32x32x16_f16(a1, bf, acc[1], 0, 0, 0);
    }

    if (counted) {
      // T4: keep this step's 3 VMEM ops (1 gB + 2 gload_lds) in flight across
      // the barrier; everything older (stage kt+1, prev gB) is forced complete.
      __builtin_amdgcn_sched_barrier(0);
      asm volatile("s_waitcnt vmcnt(3) lgkmcnt(0)" ::: "memory");
      __builtin_amdgcn_s_barrier();
      asm volatile("" ::: "memory");
      __builtin_amdgcn_sched_barrier(0);
    } else {
      __syncthreads();
    }
    wcur = wnxt;
  };

  for (int kt = 0; kt < NT - 2; kt += 3) {   // 42 chunks of 3: cur pattern 0,1,2
    step(0, kt, true);
    step(1, kt + 1, true);
    step(2, kt + 2, true);
  }
  step(0, NT - 2, false);   // tail: full drains, no staging (kt+2 >= NT)
  step(1, NT - 1, false);

  // Epilogue: 32x32 C/D (m74/m101): col(n)=lane&31, row(m)=(reg&3)+8*(reg>>2)+4*(lane>>5)
  // fp16 rounding replicated exactly: f16(y) + f16(bias) in half, widen to f32.
  {
    int n = bn + w * 32 + (lane & 31);
    __half hb = __float2half_rn(bias[n]);
#pragma unroll
    for (int ig = 0; ig < 2; ++ig) {
      int mbase = bm + ig * 32 + 4 * (lane >> 5);
#pragma unroll
      for (int reg = 0; reg < 16; ++reg) {
        int m = mbase + (reg & 3) + 8 * (reg >> 2);
        __half hy = __float2half_rn(acc[ig][reg]);
        out[(size_t)m * N_DIM + n] = __half2float(__hadd(hy, hb));
      }
    }
  }
}

// ================= fallback (R4 kernel, known-good): used only if ws too small =================
__device__ __forceinline__ uint32_t unpack_pair16(uint32_t u, int p) {
  uint32_t c0 = (u >> (4 * p)) & 3u;
  uint32_t c1 = (u >> (4 * p + 2)) & 3u;
  uint32_t lo = (c0 & 1u) * 0x3C00u + (c0 >> 1) * 0x0600u;
  uint32_t hi = (c1 & 1u) * 0x3C00u + (c1 >> 1) * 0x0600u;
  return lo | (hi << 16);
}

__global__ __launch_bounds__(NTHREADS, 2)
void ternary_gemm(const float* __restrict__ x,
                  const int*   __restrict__ pw,
                  const float* __restrict__ bias,
                  float*       __restrict__ out) {
  __shared__ __align__(16) char AsB[128 * B_STRIDE];
  __shared__ __align__(16) char BsB[128 * B_STRIDE];

  const int tid  = threadIdx.x;
  const int lane = tid & 63;
  const int w    = tid >> 6;
  const int wm   = w >> 1, wn = w & 1;
  const int bid  = blockIdx.x;
  const int bm   = (bid & 7) * 128;
  const int bn   = (bid >> 3) * 128;

  const int rT = tid >> 1, hT = tid & 1;
  const float* gA = x + (size_t)(bm + rT) * K_DIM + hT * 32;
  char* const  lA = AsB + rT * B_STRIDE + hT * 64;
  const int2* gB = (const int2*)pw + (size_t)(bn + rT) * (KP / 2) + hT;
  char* dBp[4];
#pragma unroll
  for (int h = 0; h < 4; ++h)
    dBp[h] = BsB + rT * B_STRIDE + (hT * 4 + h) * 16;

  int offA[4][2], offB[4][2];
#pragma unroll
  for (int i = 0; i < 4; ++i)
#pragma unroll
    for (int ks = 0; ks < 2; ++ks) {
      int c = ks * 4 + (lane >> 4);
      offA[i][ks] = (wm * 64 + i * 16 + (lane & 15)) * B_STRIDE + c * 16;
      offB[i][ks] = (wn * 64 + i * 16 + (lane & 15)) * B_STRIDE + c * 16;
    }

  f32x4 acc[4][4];
#pragma unroll
  for (int i = 0; i < 4; ++i)
#pragma unroll
    for (int j = 0; j < 4; ++j)
      acc[i][j] = (f32x4){0.f, 0.f, 0.f, 0.f};

  const int NT = K_DIM / BK;
  for (int kt = 0; kt < NT; ++kt) {
    __syncthreads();
    int2 wcur = gB[kt * 2];
    float4 av[8];
#pragma unroll
    for (int v = 0; v < 8; ++v) av[v] = *(const float4*)(gA + kt * BK + v * 4);
    uint32_t d0[8], d1[8];
#pragma unroll
    for (int p = 0; p < 8; ++p) d0[p] = unpack_pair16((uint32_t)wcur.x, p);
#pragma unroll
    for (int p = 0; p < 8; ++p) d1[p] = unpack_pair16((uint32_t)wcur.y, p);
    *(uint4*)dBp[0] = make_uint4(d0[0], d0[1], d0[2], d0[3]);
    *(uint4*)dBp[1] = make_uint4(d0[4], d0[5], d0[6], d0[7]);
    *(uint4*)dBp[2] = make_uint4(d1[0], d1[1], d1[2], d1[3]);
    *(uint4*)dBp[3] = make_uint4(d1[4], d1[5], d1[6], d1[7]);
#pragma unroll
    for (int v = 0; v < 4; ++v) {
      uint4 aw;
      aw.x = cvt2(av[2 * v].x, av[2 * v].y);
      aw.y = cvt2(av[2 * v].z, av[2 * v].w);
      aw.z = cvt2(av[2 * v + 1].x, av[2 * v + 1].y);
      aw.w = cvt2(av[2 * v + 1].z, av[2 * v + 1].w);
      *(uint4*)(lA + v * 16) = aw;
    }
    __syncthreads();
#pragma unroll
    for (int ks = 0; ks < 2; ++ks) {
      half8 af[4], bf[4];
#pragma unroll
      for (int i = 0; i < 4; ++i) af[i] = *(const half8*)(AsB + offA[i][ks]);
#pragma unroll
      for (int j = 0; j < 4; ++j) bf[j] = *(const half8*)(BsB + offB[j][ks]);
#pragma unroll
      for (int i = 0; i < 4; ++i)
#pragma unroll
        for (int j = 0; j < 4; ++j)
          acc[i][j] = __builtin_amdgcn_mfma_f32_16x16x32_f16(af[i], bf[j], acc[i][j], 0, 0, 0);
    }
  }
#pragma unroll
  for (int j = 0; j < 4; ++j) {
    int n = bn + wn * 64 + j * 16 + (lane & 15);
    __half hb = __float2half_rn(bias[n]);
#pragma unroll
    for (int i = 0; i < 4; ++i) {
      int m0 = bm + wm * 64 + i * 16 + (lane >> 4) * 4;
#pragma unroll
      for (int r = 0; r < 4; ++r) {
        __half hy = __float2half_rn(acc[i][j][r]);
        out[(size_t)(m0 + r) * N_DIM + n] = __half2float(__hadd(hy, hb));
      }
    }
  }
}

extern "C" void kernel_launch(void* const* d_in, const int* in_sizes, int n_in,
                              void* d_out, int out_size, void* d_ws, size_t ws_size,
                              hipStream_t stream) {
  (void)in_sizes; (void)n_in; (void)out_size;
  const float* x    = (const float*)d_in[0];
  const int*   pwp  = (const int*)d_in[1];
  const float* bias = (const float*)d_in[2];
  float*       outp = (float*)d_out;

  const size_t need = (size_t)M_DIM * K_DIM * 2;   // 16 MiB fp16 x (transposed)
  if (ws_size >= need) {
    char* xhT = (char*)d_ws;
    cvt_x_t<<<8 * 128, 256, 0, stream>>>(x, xhT);
    dim3 grid((M_DIM / BM) * (N_DIM / BN));        // 1024 blocks = 4 per CU
    ternary_gemm_dc<<<grid, NTHREADS, 0, stream>>>(xhT, pwp, bias, outp);
  } else {
    dim3 grid((M_DIM / 128) * (N_DIM / 128));      // 512 blocks
    ternary_gemm<<<grid, NTHREADS, 0, stream>>>(x, pwp, bias, outp);
  }
}